// Round 9
// baseline (320.203 us; speedup 1.0000x reference)
//
#include <hip/hip_runtime.h>

#define T_SEQ 4096
#define NDIM 64
#define BH 32
#define TN (T_SEQ * NDIM)

typedef short short8 __attribute__((ext_vector_type(8)));
typedef float f32x16 __attribute__((ext_vector_type(16)));
typedef unsigned uint2e __attribute__((ext_vector_type(2)));

// gfx950: single-op pack of two f32 -> packed bf16x2 (RNE)
static __device__ __forceinline__ unsigned packbf(float lo, float hi) {
    unsigned r;
    asm("v_cvt_pk_bf16_f32 %0, %1, %2" : "=v"(r) : "v"(lo), "v"(hi));
    return r;
}
static __device__ __forceinline__ f32x16 mfma32(short8 a, short8 b, f32x16 c) {
    return __builtin_amdgcn_mfma_f32_32x32x16_bf16(a, b, c, 0, 0, 0);
}

// Cross-half exchange (verified R5/R6)
static __device__ __forceinline__ void half_swap(unsigned &x, unsigned &y) {
#if __has_builtin(__builtin_amdgcn_permlane32_swap)
    uint2e r = __builtin_amdgcn_permlane32_swap(x, y, false, false);
    x = r[0]; y = r[1];
#else
    int sl = (((int)threadIdx.x & 63) ^ 32) << 2;
    unsigned bx = (unsigned)__builtin_amdgcn_ds_bpermute(sl, (int)x);
    unsigned by = (unsigned)__builtin_amdgcn_ds_bpermute(sl, (int)y);
    bool hi = (threadIdx.x & 32) != 0;
    unsigned nx = hi ? by : x;
    unsigned ny = hi ? y : bx;
    x = nx; y = ny;
#endif
}

// 32x32 S^T C-tile -> two A-operand frags. Verified R5/R6.
static __device__ __forceinline__ void tile_to_frags(const f32x16 &sc, short8 &f0, short8 &f1) {
    unsigned d[4][2];
#pragma unroll
    for (int g = 0; g < 4; ++g) {
        d[g][0] = packbf(sc[4 * g + 0], sc[4 * g + 1]);
        d[g][1] = packbf(sc[4 * g + 2], sc[4 * g + 3]);
    }
    half_swap(d[0][0], d[1][0]);
    half_swap(d[0][1], d[1][1]);
    half_swap(d[2][0], d[3][0]);
    half_swap(d[2][1], d[3][1]);
    union { unsigned u[4]; short8 s; } a, b;
    a.u[0] = d[0][0]; a.u[1] = d[0][1]; a.u[2] = d[1][0]; a.u[3] = d[1][1];
    b.u[0] = d[2][0]; b.u[1] = d[2][1]; b.u[2] = d[3][0]; b.u[3] = d[3][1];
    f0 = a.s; f1 = b.s;
}

// ---------- task bodies (shared by fused kernel and fallback kernels) ----------

// RoPE task: one (bh, rb) = 128 rows. Thread = one output word/iter (R7-verified).
static __device__ __forceinline__ void rope_task(const float* __restrict__ Q,
                                                 unsigned short* __restrict__ qf,
                                                 int bh, int rb, int tid) {
    const int tl = tid >> 3;
    const int hijw = tid & 7;
    const float fbase = exp2f(-0.5f * (float)hijw) * 0.15915494309189535f;
    const float2* qsrc = (const float2*)(Q + ((size_t)bh * T_SEQ + rb * 128) * NDIM);
    unsigned* qdst = (unsigned*)(qf + (size_t)bh * TN) + rb * 4096;
    const float kmul[4] = {1.0f, 0.0625f, 0.00390625f, 2.44140625e-4f};  // 2^-4kc
#pragma unroll 4
    for (int it = 0; it < 16; ++it) {
        const int kc = it & 3;
        const int row = (it >> 2) * 32 + tl;
        const int t = rb * 128 + row;
        const int np = kc * 8 + hijw;
        float2 q = qsrc[row * 32 + np];
        const float freq = fbase * kmul[kc];
        float ph = (float)t * freq;
        float ang = (ph - floorf(ph)) * 6.283185307179586f;
        float s, c;
        __sincosf(ang, &s, &c);
        float r0 = q.x * c - q.y * s;
        float r1 = q.y * c + q.x * s;
        qdst[it * 256 + tid] = packbf(r0, r1);
    }
}

// V-transpose task: one (bh, sb) tile (R0-verified body). tile = 128*65 floats in LDS.
static __device__ __forceinline__ void vtrans_task(const float* __restrict__ V,
                                                   unsigned short* __restrict__ vfr,
                                                   int bh, int sb, int tid, float* tile) {
    const float* vsrc = V + ((size_t)bh * T_SEQ + sb * 128) * NDIM;
#pragma unroll
    for (int i = 0; i < 8; ++i) {
        int e = (i * 256 + tid) * 4;
        int row = e >> 6, col = e & 63;
        float4 d4 = *(const float4*)(vsrc + e);
        tile[row * 65 + col + 0] = d4.x; tile[row * 65 + col + 1] = d4.y;
        tile[row * 65 + col + 2] = d4.z; tile[row * 65 + col + 3] = d4.w;
    }
    __syncthreads();
    unsigned short* dst = vfr + (size_t)bh * TN + (size_t)sb * 8192;
#pragma unroll
    for (int u = 0; u < 4; ++u) {
        int g = u * 256 + tid;
        int kc = g >> 7, dh = g & 127;
        int d = dh >> 1, hh = dh & 1;
        int sbase = kc * 16 + hh * 8;
        uint4 o;
        o.x = packbf(tile[(sbase + 0) * 65 + d] * 0.125f, tile[(sbase + 1) * 65 + d] * 0.125f);
        o.y = packbf(tile[(sbase + 2) * 65 + d] * 0.125f, tile[(sbase + 3) * 65 + d] * 0.125f);
        o.z = packbf(tile[(sbase + 4) * 65 + d] * 0.125f, tile[(sbase + 5) * 65 + d] * 0.125f);
        o.w = packbf(tile[(sbase + 6) * 65 + d] * 0.125f, tile[(sbase + 7) * 65 + d] * 0.125f);
        *(uint4*)(dst + g * 8) = o;
    }
}

// ---------- attention helpers (R4-verified, 72.0us) ----------
static __device__ __forceinline__ void load_ak4(const unsigned short* qfh, int sb, int ws,
                                                int lhx16, short8 (&A)[2][4]) {
    const int r32base = sb * 4 + 2 * ws;
#pragma unroll
    for (int st2 = 0; st2 < 2; ++st2)
#pragma unroll
        for (int kc = 0; kc < 4; ++kc)
            A[st2][kc] = *(const short8*)(qfh + (size_t)((r32base + st2) * 4 + kc) * 512 + lhx16);
}
static __device__ __forceinline__ void load_vf8(const unsigned short* vfh, int sb, int ws,
                                                int lhx16, short8 (&V)[4][2]) {
#pragma unroll
    for (int kc4 = 0; kc4 < 4; ++kc4) {
        const size_t base = (size_t)sb * 8192 + (size_t)(4 * ws + kc4) * 1024 + lhx16;
        V[kc4][0] = *(const short8*)(vfh + base);
        V[kc4][1] = *(const short8*)(vfh + base + 512);
    }
}
static __device__ __forceinline__ void s_phase(const short8 (&ak)[2][4], const short8 (&bq)[2][4],
                                               const f32x16 &zc, f32x16 (&sacc)[2][2]) {
#pragma unroll
    for (int st2 = 0; st2 < 2; ++st2)
#pragma unroll
        for (int tt2 = 0; tt2 < 2; ++tt2) {
            f32x16 acc = mfma32(ak[st2][0], bq[tt2][0], zc);
            acc = mfma32(ak[st2][1], bq[tt2][1], acc);
            acc = mfma32(ak[st2][2], bq[tt2][2], acc);
            sacc[st2][tt2] = mfma32(ak[st2][3], bq[tt2][3], acc);
        }
}
static __device__ __forceinline__ void transform_all(const f32x16 (&sacc)[2][2], short8 (&pa)[2][4]) {
#pragma unroll
    for (int st2 = 0; st2 < 2; ++st2)
#pragma unroll
        for (int tt2 = 0; tt2 < 2; ++tt2)
            tile_to_frags(sacc[st2][tt2], pa[tt2][2 * st2 + 0], pa[tt2][2 * st2 + 1]);
}
static __device__ __forceinline__ void o_phase(const short8 (&pa)[2][4], const short8 (&vf)[4][2],
                                               f32x16 (&oacc)[2][2]) {
#pragma unroll
    for (int kc4 = 0; kc4 < 4; ++kc4) {
        oacc[0][0] = mfma32(pa[0][kc4], vf[kc4][0], oacc[0][0]);
        oacc[0][1] = mfma32(pa[0][kc4], vf[kc4][1], oacc[0][1]);
        oacc[1][0] = mfma32(pa[1][kc4], vf[kc4][0], oacc[1][0]);
        oacc[1][1] = mfma32(pa[1][kc4], vf[kc4][1], oacc[1][1]);
    }
}

// Full attention block body (R4 VERBATIM inner loop; verified 72.0us, MfmaUtil 42.8).
// smem must provide >= 32KB scratch for the epilogue reduction.
static __device__ __forceinline__ void attn_block_body(const unsigned short* __restrict__ qf,
                                                       const unsigned short* __restrict__ vfr,
                                                       float* __restrict__ out,
                                                       int bh, int qb, int tid, char* smem) {
    const int lane = tid & 63;
    const int w = tid >> 6;
    const int ws = w >> 1, wt = w & 1;
    const int l31 = lane & 31, hi = lane >> 5;
    const int t0 = qb * 128;

    const unsigned short* qfh = qf + (size_t)bh * TN;
    const unsigned short* vfh = vfr + (size_t)bh * TN;
    float* out_h = out + (size_t)bh * TN;

    const int lhx16 = (l31 * 2 + hi) * 8;

    short8 bq[2][4];
#pragma unroll
    for (int tt2 = 0; tt2 < 2; ++tt2) {
        const int r32 = (t0 >> 5) + 2 * wt + tt2;
#pragma unroll
        for (int kc = 0; kc < 4; ++kc)
            bq[tt2][kc] = *(const short8*)(qfh + (size_t)(r32 * 4 + kc) * 512 + lhx16);
    }

    f32x16 zc;
#pragma unroll
    for (int r = 0; r < 16; ++r) zc[r] = 0.0f;

    f32x16 oacc[2][2];
#pragma unroll
    for (int a = 0; a < 2; ++a)
#pragma unroll
        for (int b = 0; b < 2; ++b)
#pragma unroll
            for (int r = 0; r < 16; ++r) oacc[a][b][r] = 0.0f;

    short8 ak[2][4], vf[4][2];
    f32x16 sacc[2][2];
    load_ak4(qfh, 0, ws, lhx16, ak);
    load_vf8(vfh, 0, ws, lhx16, vf);
    s_phase(ak, bq, zc, sacc);
    load_ak4(qfh, (1 <= qb ? 1 : qb), ws, lhx16, ak);

    for (int sb = 0; sb < qb; ++sb) {
        short8 pa[2][4];
        transform_all(sacc, pa);
        o_phase(pa, vf, oacc);
        load_vf8(vfh, sb + 1, ws, lhx16, vf);
        s_phase(ak, bq, zc, sacc);
        const int nak = (sb + 2 <= qb) ? sb + 2 : qb;
        load_ak4(qfh, nak, ws, lhx16, ak);
    }

    {
#pragma unroll
        for (int st2 = 0; st2 < 2; ++st2) {
            const int st = 2 * ws + st2;
#pragma unroll
            for (int tt2 = 0; tt2 < 2; ++tt2) {
                const int tg = (2 * wt + tt2) * 32 + l31;
#pragma unroll
                for (int r = 0; r < 16; ++r) {
                    const int sg = st * 32 + (r & 3) + 8 * (r >> 2) + 4 * hi;
                    if (sg >= tg) sacc[st2][tt2][r] = 0.0f;
                }
            }
        }
        short8 pa[2][4];
        transform_all(sacc, pa);
        o_phase(pa, vf, oacc);
    }

    float4* redp = (float4*)smem;   // [2][4][4][64] flattened
    if (ws == 1) {
#pragma unroll
        for (int tt2 = 0; tt2 < 2; ++tt2)
#pragma unroll
            for (int dd = 0; dd < 2; ++dd)
#pragma unroll
                for (int g = 0; g < 4; ++g) {
                    float4 v;
                    v.x = oacc[tt2][dd][4 * g + 0];
                    v.y = oacc[tt2][dd][4 * g + 1];
                    v.z = oacc[tt2][dd][4 * g + 2];
                    v.w = oacc[tt2][dd][4 * g + 3];
                    redp[((wt * 4 + (tt2 * 2 + dd)) * 4 + g) * 64 + lane] = v;
                }
    }
    __syncthreads();
    if (ws == 0) {
#pragma unroll
        for (int tt2 = 0; tt2 < 2; ++tt2)
#pragma unroll
            for (int dd = 0; dd < 2; ++dd) {
#pragma unroll
                for (int g = 0; g < 4; ++g) {
                    float4 o = redp[((wt * 4 + (tt2 * 2 + dd)) * 4 + g) * 64 + lane];
                    oacc[tt2][dd][4 * g + 0] += o.x;
                    oacc[tt2][dd][4 * g + 1] += o.y;
                    oacc[tt2][dd][4 * g + 2] += o.z;
                    oacc[tt2][dd][4 * g + 3] += o.w;
                }
#pragma unroll
                for (int r = 0; r < 16; ++r) {
                    const int rl = (r & 3) + 8 * (r >> 2) + 4 * hi;
                    out_h[(size_t)(t0 + 64 * wt + 32 * tt2 + rl) * NDIM + 32 * dd + l31] =
                        oacc[tt2][dd][r];
                }
            }
    }
}

// ---------- Fused kernel: prep + attn with producer->consumer flags ----------
// 3072 blocks grab tasks from a global counter (ctrl[0]):
//   task 0..1023    : rope  (bh = t&31, rb = t>>5)
//   task 1024..2047 : vtrans(bh = t&31, sb = t>>5)
//   task 2048..3071 : attn  (t' = t-2048: bh = t'&31, qb = 31-(t'>>5), longest-first)
// done[bh] = ctrl[16+bh]; each prep task: __syncthreads -> agent release fence ->
// done[bh]+=1 (target 64). attn spins (relaxed + s_sleep) then agent acquire fence.
// Liveness: grabs are monotonic, so all 2048 prep tasks are grabbed by RUNNING blocks
// before any attn task exists -> prep always completes -> no deadlock (G16-safe:
// correct under ANY dispatch order).
__global__ __launch_bounds__(256, 2) void fused_kernel(const float* __restrict__ Q,
                                                       const float* __restrict__ V,
                                                       unsigned short* __restrict__ qf,
                                                       unsigned short* __restrict__ vfr,
                                                       float* __restrict__ out,
                                                       unsigned* __restrict__ ctrl) {
    __shared__ __align__(16) char smem_all[33280];   // vtrans tile (33280) / attn red (32768)
    __shared__ unsigned sh_task;

    const int tid = threadIdx.x;
    if (tid == 0)
        sh_task = __hip_atomic_fetch_add(&ctrl[0], 1u, __ATOMIC_RELAXED,
                                         __HIP_MEMORY_SCOPE_AGENT);
    __syncthreads();
    const unsigned task = sh_task;

    if (task < 2048u) {
        const int bh = (int)(task & 31u);
        if (task < 1024u) {
            rope_task(Q, qf, bh, (int)(task >> 5), tid);
        } else {
            vtrans_task(V, vfr, bh, (int)((task - 1024u) >> 5), tid, (float*)smem_all);
        }
        __syncthreads();                    // all block stores issued
        if (tid == 0) {
            __builtin_amdgcn_fence(__ATOMIC_RELEASE, "agent");
            __hip_atomic_fetch_add(&ctrl[16 + bh], 1u, __ATOMIC_RELAXED,
                                   __HIP_MEMORY_SCOPE_AGENT);
        }
    } else {
        const unsigned t = task - 2048u;
        const int bh = (int)(t & 31u);
        const int qb = 31 - (int)(t >> 5);
        if (tid == 0) {
            while (__hip_atomic_load(&ctrl[16 + bh], __ATOMIC_RELAXED,
                                     __HIP_MEMORY_SCOPE_AGENT) < 64u)
                __builtin_amdgcn_s_sleep(16);
            __builtin_amdgcn_fence(__ATOMIC_ACQUIRE, "agent");
        }
        __syncthreads();
        __builtin_amdgcn_fence(__ATOMIC_ACQUIRE, "agent");   // all threads
        attn_block_body(qf, vfr, out, bh, qb, tid, smem_all);
    }
}

// ---------- Fallback kernels (R7-verified path, used if ws lacks ctrl room) ----------
__global__ __launch_bounds__(256) void prep_kernel(const float* __restrict__ Q,
                                                   const float* __restrict__ V,
                                                   unsigned short* __restrict__ qf,
                                                   unsigned short* __restrict__ vfr) {
    __shared__ float tile[128 * 65];
    const int bx = blockIdx.x;
    const int tid = threadIdx.x;
    if (bx < 1024) {
        rope_task(Q, qf, bx >> 5, bx & 31, tid);
    } else {
        const int b2 = bx - 1024;
        vtrans_task(V, vfr, b2 >> 5, b2 & 31, tid, tile);
    }
}
__global__ __launch_bounds__(256, 2) void attn_kernel(const unsigned short* __restrict__ qf,
                                                      const unsigned short* __restrict__ vfr,
                                                      float* __restrict__ out) {
    __shared__ __align__(16) char red[32768];
    const int blk = blockIdx.x;
    attn_block_body(qf, vfr, out, blk & 31, 31 - (blk >> 5), threadIdx.x, red);
}

extern "C" void kernel_launch(void* const* d_in, const int* in_sizes, int n_in,
                              void* d_out, int out_size, void* d_ws, size_t ws_size,
                              hipStream_t stream) {
    (void)in_sizes; (void)n_in; (void)out_size;
    const float* Q = (const float*)d_in[0];
    const float* V = (const float*)d_in[1];
    float* out = (float*)d_out;

    unsigned short* qf  = (unsigned short*)d_ws;
    unsigned short* vfr = qf + (size_t)BH * TN;
    const size_t data_bytes = (size_t)2 * BH * TN * sizeof(unsigned short);

    if (ws_size >= data_bytes + 256) {
        unsigned* ctrl = (unsigned*)((char*)d_ws + data_bytes);
        (void)hipMemsetAsync(ctrl, 0, 256, stream);
        fused_kernel<<<3072, 256, 0, stream>>>(Q, V, qf, vfr, out, ctrl);
    } else {
        prep_kernel<<<2048, 256, 0, stream>>>(Q, V, qf, vfr);
        attn_kernel<<<BH * 32, 256, 0, stream>>>(qf, vfr, out);
    }
}